// Round 6
// baseline (2714.693 us; speedup 1.0000x reference)
//
#include <hip/hip_runtime.h>
#include <hip/hip_bf16.h>

#define EPSF 1e-8f

typedef __attribute__((ext_vector_type(8))) short short8v;
typedef __attribute__((ext_vector_type(4))) float float4v;

static __device__ __forceinline__ unsigned short f2bf_bits(float x)
{
    return __builtin_bit_cast(unsigned short, __float2bfloat16(x));
}

// ---------------------------------------------------------------------------
// Bw2 transform: pc_w f32 [256oc][256ic][81k] -> coalesced per-wave chunks:
//   chunk_id = ((kidx*8+icc)*4+wc)*4+nt ; within chunk lane(slot*16+r16)*8+i
//   element = pc_w[oc=wc*64+nt*16+r16][ic=icc*32+slot*8+i][kidx]  (bf16)
// block = oc (256), 256 thr. pc_w row staged bf16-bits in LDS (41.5KB).
// ---------------------------------------------------------------------------
__global__ __launch_bounds__(256) void k_bw2(const float* __restrict__ pw,
                                             __hip_bfloat16* __restrict__ Bw2)
{
    const int oc = blockIdx.x;
    const int t = threadIdx.x;
    __shared__ unsigned short wl[20736];   // [ic][k] bf16 bits
    for (int i = t; i < 20736; i += 256)
        wl[i] = f2bf_bits(pw[(size_t)oc * 20736 + i]);
    __syncthreads();
    const int r16 = oc & 15, nt = (oc >> 4) & 3, wcq = oc >> 6;
    for (int e = t; e < 2592; e += 256) {
        const int kidx = e >> 5, icc = (e >> 2) & 7, slot = e & 3;
        short8v v;
        #pragma unroll
        for (int i = 0; i < 8; ++i)
            v[i] = (short)wl[(icc * 32 + slot * 8 + i) * 81 + kidx];
        const int chunk = ((kidx * 8 + icc) * 4 + wcq) * 4 + nt;
        *(short8v*)(Bw2 + (size_t)chunk * 512 + (slot * 16 + r16) * 8) = v;
    }
}

// ---------------------------------------------------------------------------
// conv1: image[512,1,28,28] * cw[256,1,9,9] + cb -> relu
//   -> x_t bf16 [b][icc=8][pos=400][64B unit, slot-XOR-permuted]
//   pos = h*20 + (w&1)*10 + (w>>1); unit byte: ((slot ^ ((pos>>1)&3))<<4)+ic8*2
// block = b, 256 threads = c. Image in LDS.
// ---------------------------------------------------------------------------
__global__ __launch_bounds__(256) void k_conv1(const float* __restrict__ img,
                                               const float* __restrict__ cw,
                                               const float* __restrict__ cb,
                                               __hip_bfloat16* __restrict__ xt)
{
    const int b = blockIdx.x;
    const int c = threadIdx.x;
    __shared__ float simg[784];
    for (int i = c; i < 784; i += 256) simg[i] = img[b * 784 + i];
    float wreg[81];
    const float* wp = cw + c * 81;
    #pragma unroll
    for (int k = 0; k < 81; ++k) wreg[k] = wp[k];
    const float bias = cb[c];
    __syncthreads();

    const int icc = c >> 5, slot = (c >> 3) & 3, ic8 = c & 7;
    char* xbase = (char*)xt + ((size_t)b * 8 + icc) * 25600;

    for (int h = 0; h < 20; ++h) {
        for (int wg = 0; wg < 5; ++wg) {
            float acc[4] = {bias, bias, bias, bias};
            #pragma unroll
            for (int ky = 0; ky < 9; ++ky) {
                const float* rp = &simg[(h + ky) * 28 + wg * 4];
                float v[12];
                #pragma unroll
                for (int i = 0; i < 12; ++i) v[i] = rp[i];
                #pragma unroll
                for (int kx = 0; kx < 9; ++kx) {
                    const float wv = wreg[ky * 9 + kx];
                    #pragma unroll
                    for (int i = 0; i < 4; ++i)
                        acc[i] = fmaf(v[kx + i], wv, acc[i]);
                }
            }
            #pragma unroll
            for (int i = 0; i < 4; ++i) {
                int w = wg * 4 + i;
                float av = fmaxf(acc[i], 0.f);
                int pos = h * 20 + (w & 1) * 10 + (w >> 1);
                int off = pos * 64 + ((slot ^ ((pos >> 1) & 3)) << 4) + ic8 * 2;
                *(unsigned short*)(xbase + off) = f2bf_bits(av);
            }
        }
    }
}

// ---------------------------------------------------------------------------
// async stage of one icc-chunk (2 images, 51200 B) into LDS via global_load_lds
// ---------------------------------------------------------------------------
__device__ __forceinline__ void stage_x(const __hip_bfloat16* __restrict__ xt,
                                        char* dst, int b0, int icc, int t)
{
    const __hip_bfloat16* base0 = xt + ((size_t)(b0    ) * 8 + icc) * 12800;
    const __hip_bfloat16* base1 = xt + ((size_t)(b0 + 1) * 8 + icc) * 12800;
    #pragma unroll
    for (int k = 0; k < 6; ++k) {
        const int unit = t + k * 512;
        const __hip_bfloat16* gp = (unit < 1600) ? (base0 + unit * 8)
                                                 : (base1 + (unit - 1600) * 8);
        __builtin_amdgcn_global_load_lds(
            (const __attribute__((address_space(1))) unsigned int*)gp,
            (__attribute__((address_space(3))) unsigned int*)(dst + unit * 16),
            16, 0, 0);
    }
    if (t < 128) {
        const int unit = 3072 + t;
        const __hip_bfloat16* gp = base1 + (unit - 1600) * 8;
        __builtin_amdgcn_global_load_lds(
            (const __attribute__((address_space(1))) unsigned int*)gp,
            (__attribute__((address_space(3))) unsigned int*)(dst + unit * 16),
            16, 0, 0);
    }
}

// ---------------------------------------------------------------------------
// conv2 via MFMA: grid 256 (2 b each), 512 thr = 8 waves (wr=img, wc=64-oc).
// Double-buffered LDS (2x51.2KB), async global_load_lds, 1 barrier per icc.
// B from coalesced Bw2 (1KB contiguous per wave-load).
// ---------------------------------------------------------------------------
__global__ __launch_bounds__(512) void k_conv2(const __hip_bfloat16* __restrict__ xt,
                                               const __hip_bfloat16* __restrict__ Bw2,
                                               const float* __restrict__ pcb,
                                               float* __restrict__ u)
{
    const int b0 = blockIdx.x * 2;
    const int t = threadIdx.x;
    const int lane = t & 63, wid = t >> 6;
    const int wr = wid >> 2, wc = wid & 3;
    const int r16 = lane & 15, slot = lane >> 4;

    __shared__ alignas(16) char xs[2][51200];

    int lc[3];
    #pragma unroll
    for (int mt = 0; mt < 3; ++mt) {
        int hw = mt * 16 + r16;
        if (hw >= 36) hw = 0;
        int h = hw / 6, w = hw - h * 6;
        lc[mt] = 40 * h + w;
    }

    float4v acc[3][4];
    #pragma unroll
    for (int mt = 0; mt < 3; ++mt)
        #pragma unroll
        for (int nt = 0; nt < 4; ++nt)
            acc[mt][nt] = (float4v){0.f, 0.f, 0.f, 0.f};

    stage_x(xt, xs[0], b0, 0, t);
    __syncthreads();

    for (int icc = 0; icc < 8; ++icc) {
        const int cur = icc & 1;
        if (icc < 7) stage_x(xt, xs[cur ^ 1], b0, icc + 1, t);

        const char* xw = xs[cur] + wr * 25600;
        const size_t bK = ((size_t)icc * 4 + wc) * 2048 + lane * 8;

        #pragma unroll 3
        for (int kidx = 0; kidx < 81; ++kidx) {
            int ky = kidx / 9, kx = kidx - ky * 9;
            int scalK = 20 * ky + 10 * (kx & 1) + (kx >> 1);
            short8v a[3];
            #pragma unroll
            for (int mt = 0; mt < 3; ++mt) {
                int pos = lc[mt] + scalK;
                int off = pos * 64 + (((slot ^ (pos >> 1)) & 3) << 4);
                a[mt] = *(const short8v*)(xw + off);
            }
            const __hip_bfloat16* bp = Bw2 + (size_t)kidx * 65536 + bK;
            short8v bv[4];
            #pragma unroll
            for (int nt = 0; nt < 4; ++nt)
                bv[nt] = *(const short8v*)(bp + nt * 512);
            #pragma unroll
            for (int mt = 0; mt < 3; ++mt)
                #pragma unroll
                for (int nt = 0; nt < 4; ++nt)
                    acc[mt][nt] = __builtin_amdgcn_mfma_f32_16x16x32_bf16(a[mt], bv[nt], acc[mt][nt], 0, 0, 0);
        }
        __syncthreads();
    }

    // epilogue: D row(hw) = slot*4+i, col(oc) = r16
    const int b = b0 + wr;
    #pragma unroll
    for (int mt = 0; mt < 3; ++mt) {
        int hwb = mt * 16 + slot * 4;
        if (hwb < 36) {
            #pragma unroll
            for (int nt = 0; nt < 4; ++nt) {
                int oc = wc * 64 + nt * 16 + r16;
                float pb = pcb[oc];
                float4v v = acc[mt][nt];
                v.x += pb; v.y += pb; v.z += pb; v.w += pb;
                *(float4v*)(u + (size_t)b * 9216 + oc * 36 + hwb) = v;
            }
        }
    }
}

// ---------------------------------------------------------------------------
// squash groups of 8 (in place)
// ---------------------------------------------------------------------------
__global__ void k_squash_u(float* __restrict__ u, int ngroups)
{
    int g = blockIdx.x * blockDim.x + threadIdx.x;
    if (g >= ngroups) return;
    float4v* p = (float4v*)(u + (size_t)g * 8);
    float4v a = p[0], c = p[1];
    float sq = a.x * a.x + a.y * a.y + a.z * a.z + a.w * a.w
             + c.x * c.x + c.y * c.y + c.z * c.z + c.w * c.w;
    float scale = (sq / (1.f + sq)) / sqrtf(sq + EPSF);
    a *= scale; c *= scale;
    p[0] = a; p[1] = c;
}

// ---------------------------------------------------------------------------
// routing iteration: grid (72 r-chunks of 16, 16 b-chunks of 32), 256 thr.
// W chunk f32 in LDS (80KB, XOR-swizzled). 2 images per W-read (uhA/uhB).
// partial s_j -> shfl-reduce over rl -> atomicAdd global s[b][160].
// ---------------------------------------------------------------------------
__global__ __launch_bounds__(256, 2) void k_route3(const float* __restrict__ u,
                                                   const float* __restrict__ W,
                                                   const float* __restrict__ vsum,
                                                   float* __restrict__ s, int iter)
{
    const int r0 = blockIdx.x * 16;
    const int b0 = blockIdx.y * 32;
    const int t = threadIdx.x;
    const int oq = t & 3, rl = (t >> 2) & 15, bl = t >> 6;

    __shared__ alignas(16) float Wl[16 * 320 * 4];  // 80KB, swizzled

    for (int e = t; e < 5120; e += 256) {
        int rl_ = e / 320;
        int rest = e - rl_ * 320;
        float4v val = *(const float4v*)(W + (size_t)(r0 + rl_) * 1280 + rest * 4);
        *(float4v*)(Wl + ((size_t)rl_ * 320 + (rest ^ (rl_ & 7))) * 4) = val;
    }
    __syncthreads();

    const int m = rl & 7;
    int xo[8];
    #pragma unroll
    for (int z = 0; z < 8; ++z) xo[z] = (z ^ m) * 16;
    const char* wbase = (const char*)Wl + ((size_t)rl * 320 + oq * 8) * 16;

    for (int pp = 0; pp < 4; ++pp) {
        const int bA = b0 + bl * 8 + pp * 2;
        const int bB = bA + 1;
        const float4v* upA = (const float4v*)(u + (size_t)bA * 9216 + (r0 + rl) * 8);
        const float4v* upB = (const float4v*)(u + (size_t)bB * 9216 + (r0 + rl) * 8);
        float4v uA0 = upA[0], uA1 = upA[1];
        float4v uB0 = upB[0], uB1 = upB[1];

        float uhA[10][4], uhB[10][4];
        #pragma unroll
        for (int j = 0; j < 10; ++j) {
            const char* pj = wbase + j * 512;
            #pragma unroll
            for (int oo = 0; oo < 4; ++oo) {
                float4v wlo = *(const float4v*)(pj + xo[oo * 2]);
                float4v whi = *(const float4v*)(pj + xo[oo * 2 + 1]);
                uhA[j][oo] = wlo.x * uA0.x + wlo.y * uA0.y + wlo.z * uA0.z + wlo.w * uA0.w
                           + whi.x * uA1.x + whi.y * uA1.y + whi.z * uA1.z + whi.w * uA1.w;
                uhB[j][oo] = wlo.x * uB0.x + wlo.y * uB0.y + wlo.z * uB0.z + wlo.w * uB0.w
                           + whi.x * uB1.x + whi.y * uB1.y + whi.z * uB1.z + whi.w * uB1.w;
            }
        }

        #pragma unroll 2
        for (int half = 0; half < 2; ++half) {
            const int b = half ? bB : bA;
            float (*uh)[4] = half ? uhB : uhA;
            float cj[10];
            if (iter > 0) {
                float q[10];
                #pragma unroll
                for (int j = 0; j < 10; ++j) {
                    float4v vj = *(const float4v*)(vsum + (size_t)b * 160 + j * 16 + oq * 4);
                    float qp = uh[j][0] * vj.x + uh[j][1] * vj.y + uh[j][2] * vj.z + uh[j][3] * vj.w;
                    qp += __shfl_xor(qp, 1);
                    qp += __shfl_xor(qp, 2);
                    q[j] = qp;
                }
                float mx = q[0];
                #pragma unroll
                for (int j = 1; j < 10; ++j) mx = fmaxf(mx, q[j]);
                float ssum = 0.f;
                #pragma unroll
                for (int j = 0; j < 10; ++j) { cj[j] = __expf(q[j] - mx); ssum += cj[j]; }
                float inv = 1.f / ssum;
                #pragma unroll
                for (int j = 0; j < 10; ++j) cj[j] *= inv;
            } else {
                #pragma unroll
                for (int j = 0; j < 10; ++j) cj[j] = 0.1f;
            }

            #pragma unroll
            for (int j = 0; j < 10; ++j)
                #pragma unroll
                for (int oo = 0; oo < 4; ++oo) {
                    float v = cj[j] * uh[j][oo];
                    v += __shfl_xor(v, 4);
                    v += __shfl_xor(v, 8);
                    v += __shfl_xor(v, 16);
                    v += __shfl_xor(v, 32);
                    uh[j][oo] = v;
                }
            if (rl == 0) {
                #pragma unroll
                for (int j = 0; j < 10; ++j)
                    #pragma unroll
                    for (int oo = 0; oo < 4; ++oo)
                        atomicAdd(&s[(size_t)b * 160 + j * 16 + oq * 4 + oo], uh[j][oo]);
            }
        }
    }
}

// ---------------------------------------------------------------------------
// finish: squash s -> v, vsum += v, zero s; iter==2 writes outputs
// ---------------------------------------------------------------------------
__global__ void k_finish(float* __restrict__ s, float* __restrict__ vsum,
                         const int* __restrict__ label, float* __restrict__ obj,
                         float* __restrict__ yprob, float* __restrict__ masked, int iter)
{
    const int b = blockIdx.x, t = threadIdx.x;
    if (t < 160) {
        float sv = s[b * 160 + t];
        float sq = sv * sv;
        sq += __shfl_xor(sq, 1); sq += __shfl_xor(sq, 2);
        sq += __shfl_xor(sq, 4); sq += __shfl_xor(sq, 8);
        float v = sv * (sq / (1.f + sq)) / sqrtf(sq + EPSF);
        float pv = (iter > 0) ? vsum[b * 160 + t] : 0.f;
        vsum[b * 160 + t] = pv + v;
        s[b * 160 + t] = 0.f;
        if (iter == 2) {
            obj[b * 160 + t] = v;
            float vv = v * v;
            vv += __shfl_xor(vv, 1); vv += __shfl_xor(vv, 2);
            vv += __shfl_xor(vv, 4); vv += __shfl_xor(vv, 8);
            int j = t >> 4;
            if ((t & 15) == 0) yprob[b * 10 + j] = sqrtf(vv + EPSF);
            masked[b * 160 + t] = (label[b] == j) ? v : 0.f;
        }
    }
}

// ---------------------------------------------------------------------------
// decoder GEMM: C[m,n] = act(bias[n] + sum_k A[m,k]*Wt[n,k]); M=512.
// ---------------------------------------------------------------------------
__global__ void k_mlp(const float* __restrict__ A, const float* __restrict__ Wt,
                      const float* __restrict__ bias, float* __restrict__ C,
                      int N, int K, int act)
{
    const int m0 = blockIdx.x * 32;
    const int n0 = blockIdx.y * 32;
    const int t  = threadIdx.x;
    const int tn = t & 31, tg = t >> 5;
    __shared__ float As[32][33];
    __shared__ float Ws[32][33];
    float acc[4] = {0.f, 0.f, 0.f, 0.f};
    for (int k0 = 0; k0 < K; k0 += 32) {
        __syncthreads();
        for (int idx = t; idx < 1024; idx += 256) {
            int rr = idx >> 5, kk = idx & 31;
            As[rr][kk] = A[(size_t)(m0 + rr) * K + k0 + kk];
            int n = n0 + rr;
            Ws[rr][kk] = (n < N) ? Wt[(size_t)n * K + k0 + kk] : 0.f;
        }
        __syncthreads();
        #pragma unroll 8
        for (int kk = 0; kk < 32; ++kk) {
            float bv = Ws[tn][kk];
            #pragma unroll
            for (int i = 0; i < 4; ++i)
                acc[i] += As[tg * 4 + i][kk] * bv;
        }
    }
    int n = n0 + tn;
    if (n < N) {
        float bs = bias[n];
        #pragma unroll
        for (int i = 0; i < 4; ++i) {
            float vv = acc[i] + bs;
            vv = (act == 0) ? fmaxf(vv, 0.f) : 1.f / (1.f + expf(-vv));
            C[(size_t)(m0 + tg * 4 + i) * N + n] = vv;
        }
    }
}

// ---------------------------------------------------------------------------
extern "C" void kernel_launch(void* const* d_in, const int* in_sizes, int n_in,
                              void* d_out, int out_size, void* d_ws, size_t ws_size,
                              hipStream_t stream)
{
    const float* image  = (const float*)d_in[0];
    const int*   label  = (const int*)  d_in[1];
    const float* conv_w = (const float*)d_in[2];
    const float* conv_b = (const float*)d_in[3];
    const float* pc_w   = (const float*)d_in[4];
    const float* pc_b   = (const float*)d_in[5];
    const float* Wrt    = (const float*)d_in[6];
    const float* dw1 = (const float*)d_in[7];
    const float* db1 = (const float*)d_in[8];
    const float* dw2 = (const float*)d_in[9];
    const float* db2 = (const float*)d_in[10];
    const float* dw3 = (const float*)d_in[11];
    const float* db3 = (const float*)d_in[12];
    float* out = (float*)d_out;

    char* p = (char*)d_ws;
    __hip_bfloat16* xt  = (__hip_bfloat16*)p; p += 104857600;
    float* u      = (float*)p; p += 18874368;
    __hip_bfloat16* Bw2 = (__hip_bfloat16*)p; p += 10616832;
    float* s      = (float*)p; p += 327680;
    float* vsum   = (float*)p; p += 327680;
    float* masked = (float*)p; p += 327680;
    float* h1     = (float*)p; p += 1048576;
    float* h2     = (float*)p; p += 2097152;

    float* obj   = out;            // [512,10,16,1]
    float* recon = out + 81920;    // [512,1,28,28]
    float* yprob = out + 483328;   // [512,10]

    (void)hipMemsetAsync(s, 0, 327680, stream);
    k_bw2<<<256, 256, 0, stream>>>(pc_w, Bw2);
    k_conv1<<<512, 256, 0, stream>>>(image, conv_w, conv_b, xt);
    k_conv2<<<256, 512, 0, stream>>>(xt, Bw2, pc_b, u);
    k_squash_u<<<2304, 256, 0, stream>>>(u, 589824);
    for (int it = 0; it < 3; ++it) {
        k_route3<<<dim3(72, 16), 256, 0, stream>>>(u, Wrt, vsum, s, it);
        k_finish<<<512, 192, 0, stream>>>(s, vsum, label, obj, yprob, masked, it);
    }
    k_mlp<<<dim3(16, 16), 256, 0, stream>>>(masked, dw1, db1, h1, 512, 160, 0);
    k_mlp<<<dim3(16, 32), 256, 0, stream>>>(h1, dw2, db2, h2, 1024, 512, 0);
    k_mlp<<<dim3(16, 25), 256, 0, stream>>>(h2, dw3, db3, recon, 784, 1024, 1);
}

// Round 7
// 2075.630 us; speedup vs baseline: 1.3079x; 1.3079x over previous
//
#include <hip/hip_runtime.h>
#include <hip/hip_bf16.h>

#define EPSF 1e-8f

typedef __attribute__((ext_vector_type(8))) short short8v;
typedef __attribute__((ext_vector_type(4))) float float4v;

static __device__ __forceinline__ unsigned short f2bf_bits(float x)
{
    return __builtin_bit_cast(unsigned short, __float2bfloat16(x));
}

// ---------------------------------------------------------------------------
// Bw2 transform: pc_w f32 [256oc][256ic][81k] -> coalesced per-wave chunks:
//   chunk_id = ((kidx*8+icc)*4+wc)*4+nt ; within chunk lane(slot*16+r16)*8+i
// ---------------------------------------------------------------------------
__global__ __launch_bounds__(256) void k_bw2(const float* __restrict__ pw,
                                             __hip_bfloat16* __restrict__ Bw2)
{
    const int oc = blockIdx.x;
    const int t = threadIdx.x;
    __shared__ unsigned short wl[20736];   // [ic][k] bf16 bits
    for (int i = t; i < 20736; i += 256)
        wl[i] = f2bf_bits(pw[(size_t)oc * 20736 + i]);
    __syncthreads();
    const int r16 = oc & 15, nt = (oc >> 4) & 3, wcq = oc >> 6;
    for (int e = t; e < 2592; e += 256) {
        const int kidx = e >> 5, icc = (e >> 2) & 7, slot = e & 3;
        short8v v;
        #pragma unroll
        for (int i = 0; i < 8; ++i)
            v[i] = (short)wl[(icc * 32 + slot * 8 + i) * 81 + kidx];
        const int chunk = ((kidx * 8 + icc) * 4 + wcq) * 4 + nt;
        *(short8v*)(Bw2 + (size_t)chunk * 512 + (slot * 16 + r16) * 8) = v;
    }
}

// ---------------------------------------------------------------------------
// conv1: image[512,1,28,28] * cw[256,1,9,9] + cb -> relu
//   -> x_t bf16 [b][icc=8][pos=400][64B unit, slot-XOR-permuted]
// ---------------------------------------------------------------------------
__global__ __launch_bounds__(256) void k_conv1(const float* __restrict__ img,
                                               const float* __restrict__ cw,
                                               const float* __restrict__ cb,
                                               __hip_bfloat16* __restrict__ xt)
{
    const int b = blockIdx.x;
    const int c = threadIdx.x;
    __shared__ float simg[784];
    for (int i = c; i < 784; i += 256) simg[i] = img[b * 784 + i];
    float wreg[81];
    const float* wp = cw + c * 81;
    #pragma unroll
    for (int k = 0; k < 81; ++k) wreg[k] = wp[k];
    const float bias = cb[c];
    __syncthreads();

    const int icc = c >> 5, slot = (c >> 3) & 3, ic8 = c & 7;
    char* xbase = (char*)xt + ((size_t)b * 8 + icc) * 25600;

    for (int h = 0; h < 20; ++h) {
        for (int wg = 0; wg < 5; ++wg) {
            float acc[4] = {bias, bias, bias, bias};
            #pragma unroll
            for (int ky = 0; ky < 9; ++ky) {
                const float* rp = &simg[(h + ky) * 28 + wg * 4];
                float v[12];
                #pragma unroll
                for (int i = 0; i < 12; ++i) v[i] = rp[i];
                #pragma unroll
                for (int kx = 0; kx < 9; ++kx) {
                    const float wv = wreg[ky * 9 + kx];
                    #pragma unroll
                    for (int i = 0; i < 4; ++i)
                        acc[i] = fmaf(v[kx + i], wv, acc[i]);
                }
            }
            #pragma unroll
            for (int i = 0; i < 4; ++i) {
                int w = wg * 4 + i;
                float av = fmaxf(acc[i], 0.f);
                int pos = h * 20 + (w & 1) * 10 + (w >> 1);
                int off = pos * 64 + ((slot ^ ((pos >> 1) & 3)) << 4) + ic8 * 2;
                *(unsigned short*)(xbase + off) = f2bf_bits(av);
            }
        }
    }
}

// ---------------------------------------------------------------------------
// async stage of one icc-chunk (2 images, 51200 B) into LDS via global_load_lds
// ---------------------------------------------------------------------------
__device__ __forceinline__ void stage_x(const __hip_bfloat16* __restrict__ xt,
                                        char* dst, int b0, int icc, int t)
{
    const __hip_bfloat16* base0 = xt + ((size_t)(b0    ) * 8 + icc) * 12800;
    const __hip_bfloat16* base1 = xt + ((size_t)(b0 + 1) * 8 + icc) * 12800;
    #pragma unroll
    for (int k = 0; k < 6; ++k) {
        const int unit = t + k * 512;
        const __hip_bfloat16* gp = (unit < 1600) ? (base0 + unit * 8)
                                                 : (base1 + (unit - 1600) * 8);
        __builtin_amdgcn_global_load_lds(
            (const __attribute__((address_space(1))) unsigned int*)gp,
            (__attribute__((address_space(3))) unsigned int*)(dst + unit * 16),
            16, 0, 0);
    }
    if (t < 128) {
        const int unit = 3072 + t;
        const __hip_bfloat16* gp = base1 + (unit - 1600) * 8;
        __builtin_amdgcn_global_load_lds(
            (const __attribute__((address_space(1))) unsigned int*)gp,
            (__attribute__((address_space(3))) unsigned int*)(dst + unit * 16),
            16, 0, 0);
    }
}

// ---------------------------------------------------------------------------
// conv2 via MFMA: grid 256 (2 b each), 512 thr = 8 waves (wr=img, wc=64-oc).
// Double-buffered LDS (2x51.2KB), async global_load_lds, 1 barrier per icc.
// ---------------------------------------------------------------------------
__global__ __launch_bounds__(512) void k_conv2(const __hip_bfloat16* __restrict__ xt,
                                               const __hip_bfloat16* __restrict__ Bw2,
                                               const float* __restrict__ pcb,
                                               float* __restrict__ u)
{
    const int b0 = blockIdx.x * 2;
    const int t = threadIdx.x;
    const int lane = t & 63, wid = t >> 6;
    const int wr = wid >> 2, wc = wid & 3;
    const int r16 = lane & 15, slot = lane >> 4;

    __shared__ alignas(16) char xs[2][51200];

    int lc[3];
    #pragma unroll
    for (int mt = 0; mt < 3; ++mt) {
        int hw = mt * 16 + r16;
        if (hw >= 36) hw = 0;
        int h = hw / 6, w = hw - h * 6;
        lc[mt] = 40 * h + w;
    }

    float4v acc[3][4];
    #pragma unroll
    for (int mt = 0; mt < 3; ++mt)
        #pragma unroll
        for (int nt = 0; nt < 4; ++nt)
            acc[mt][nt] = (float4v){0.f, 0.f, 0.f, 0.f};

    stage_x(xt, xs[0], b0, 0, t);
    __syncthreads();

    for (int icc = 0; icc < 8; ++icc) {
        const int cur = icc & 1;
        if (icc < 7) stage_x(xt, xs[cur ^ 1], b0, icc + 1, t);

        const char* xw = xs[cur] + wr * 25600;
        const size_t bK = ((size_t)icc * 4 + wc) * 2048 + lane * 8;

        #pragma unroll 3
        for (int kidx = 0; kidx < 81; ++kidx) {
            int ky = kidx / 9, kx = kidx - ky * 9;
            int scalK = 20 * ky + 10 * (kx & 1) + (kx >> 1);
            short8v a[3];
            #pragma unroll
            for (int mt = 0; mt < 3; ++mt) {
                int pos = lc[mt] + scalK;
                int off = pos * 64 + (((slot ^ (pos >> 1)) & 3) << 4);
                a[mt] = *(const short8v*)(xw + off);
            }
            const __hip_bfloat16* bp = Bw2 + (size_t)kidx * 65536 + bK;
            short8v bv[4];
            #pragma unroll
            for (int nt = 0; nt < 4; ++nt)
                bv[nt] = *(const short8v*)(bp + nt * 512);
            #pragma unroll
            for (int mt = 0; mt < 3; ++mt)
                #pragma unroll
                for (int nt = 0; nt < 4; ++nt)
                    acc[mt][nt] = __builtin_amdgcn_mfma_f32_16x16x32_bf16(a[mt], bv[nt], acc[mt][nt], 0, 0, 0);
        }
        __syncthreads();
    }

    // epilogue: D row(hw) = slot*4+i, col(oc) = r16
    const int b = b0 + wr;
    #pragma unroll
    for (int mt = 0; mt < 3; ++mt) {
        int hwb = mt * 16 + slot * 4;
        if (hwb < 36) {
            #pragma unroll
            for (int nt = 0; nt < 4; ++nt) {
                int oc = wc * 64 + nt * 16 + r16;
                float pb = pcb[oc];
                float4v v = acc[mt][nt];
                v.x += pb; v.y += pb; v.z += pb; v.w += pb;
                *(float4v*)(u + (size_t)b * 9216 + oc * 36 + hwb) = v;
            }
        }
    }
}

// ---------------------------------------------------------------------------
// squash groups of 8 (in place)
// ---------------------------------------------------------------------------
__global__ void k_squash_u(float* __restrict__ u, int ngroups)
{
    int g = blockIdx.x * blockDim.x + threadIdx.x;
    if (g >= ngroups) return;
    float4v* p = (float4v*)(u + (size_t)g * 8);
    float4v a = p[0], c = p[1];
    float sq = a.x * a.x + a.y * a.y + a.z * a.z + a.w * a.w
             + c.x * c.x + c.y * c.y + c.z * c.z + c.w * c.w;
    float scale = (sq / (1.f + sq)) / sqrtf(sq + EPSF);
    a *= scale; c *= scale;
    p[0] = a; p[1] = c;
}

// ---------------------------------------------------------------------------
// routing iteration: grid (72 r-chunks of 16, 16 b-chunks of 32), 256 thr.
// W chunk f32 in LDS (80KB, XOR-swizzled). 2 images per W-read (uhA/uhB).
// partial s_j -> shfl-reduce over rl -> STORE to spart[rc][b][160] (no atomics)
// ---------------------------------------------------------------------------
__global__ __launch_bounds__(256, 2) void k_route3(const float* __restrict__ u,
                                                   const float* __restrict__ W,
                                                   const float* __restrict__ vsum,
                                                   float* __restrict__ spart, int iter)
{
    const int rc = blockIdx.x;
    const int r0 = rc * 16;
    const int b0 = blockIdx.y * 32;
    const int t = threadIdx.x;
    const int oq = t & 3, rl = (t >> 2) & 15, bl = t >> 6;

    __shared__ alignas(16) float Wl[16 * 320 * 4];  // 80KB, swizzled

    for (int e = t; e < 5120; e += 256) {
        int rl_ = e / 320;
        int rest = e - rl_ * 320;
        float4v val = *(const float4v*)(W + (size_t)(r0 + rl_) * 1280 + rest * 4);
        *(float4v*)(Wl + ((size_t)rl_ * 320 + (rest ^ (rl_ & 7))) * 4) = val;
    }
    __syncthreads();

    const int m = rl & 7;
    int xo[8];
    #pragma unroll
    for (int z = 0; z < 8; ++z) xo[z] = (z ^ m) * 16;
    const char* wbase = (const char*)Wl + ((size_t)rl * 320 + oq * 8) * 16;

    for (int pp = 0; pp < 4; ++pp) {
        const int bA = b0 + bl * 8 + pp * 2;
        const int bB = bA + 1;
        const float4v* upA = (const float4v*)(u + (size_t)bA * 9216 + (r0 + rl) * 8);
        const float4v* upB = (const float4v*)(u + (size_t)bB * 9216 + (r0 + rl) * 8);
        float4v uA0 = upA[0], uA1 = upA[1];
        float4v uB0 = upB[0], uB1 = upB[1];

        float uhA[10][4], uhB[10][4];
        #pragma unroll
        for (int j = 0; j < 10; ++j) {
            const char* pj = wbase + j * 512;
            #pragma unroll
            for (int oo = 0; oo < 4; ++oo) {
                float4v wlo = *(const float4v*)(pj + xo[oo * 2]);
                float4v whi = *(const float4v*)(pj + xo[oo * 2 + 1]);
                uhA[j][oo] = wlo.x * uA0.x + wlo.y * uA0.y + wlo.z * uA0.z + wlo.w * uA0.w
                           + whi.x * uA1.x + whi.y * uA1.y + whi.z * uA1.z + whi.w * uA1.w;
                uhB[j][oo] = wlo.x * uB0.x + wlo.y * uB0.y + wlo.z * uB0.z + wlo.w * uB0.w
                           + whi.x * uB1.x + whi.y * uB1.y + whi.z * uB1.z + whi.w * uB1.w;
            }
        }

        #pragma unroll 2
        for (int half = 0; half < 2; ++half) {
            const int b = half ? bB : bA;
            float (*uh)[4] = half ? uhB : uhA;
            float cj[10];
            if (iter > 0) {
                float q[10];
                #pragma unroll
                for (int j = 0; j < 10; ++j) {
                    float4v vj = *(const float4v*)(vsum + (size_t)b * 160 + j * 16 + oq * 4);
                    float qp = uh[j][0] * vj.x + uh[j][1] * vj.y + uh[j][2] * vj.z + uh[j][3] * vj.w;
                    qp += __shfl_xor(qp, 1);
                    qp += __shfl_xor(qp, 2);
                    q[j] = qp;
                }
                float mx = q[0];
                #pragma unroll
                for (int j = 1; j < 10; ++j) mx = fmaxf(mx, q[j]);
                float ssum = 0.f;
                #pragma unroll
                for (int j = 0; j < 10; ++j) { cj[j] = __expf(q[j] - mx); ssum += cj[j]; }
                float inv = 1.f / ssum;
                #pragma unroll
                for (int j = 0; j < 10; ++j) cj[j] *= inv;
            } else {
                #pragma unroll
                for (int j = 0; j < 10; ++j) cj[j] = 0.1f;
            }

            #pragma unroll
            for (int j = 0; j < 10; ++j)
                #pragma unroll
                for (int oo = 0; oo < 4; ++oo) {
                    float v = cj[j] * uh[j][oo];
                    v += __shfl_xor(v, 4);
                    v += __shfl_xor(v, 8);
                    v += __shfl_xor(v, 16);
                    v += __shfl_xor(v, 32);
                    uh[j][oo] = v;
                }
            if (rl == 0) {
                float* dst = spart + ((size_t)rc * 512 + b) * 160 + oq * 4;
                #pragma unroll
                for (int j = 0; j < 10; ++j) {
                    float4v v4 = {uh[j][0], uh[j][1], uh[j][2], uh[j][3]};
                    *(float4v*)(dst + j * 16) = v4;
                }
            }
        }
    }
}

// ---------------------------------------------------------------------------
// finish: sum 72 partials -> squash -> v; vsum update; iter==2 writes outputs
// ---------------------------------------------------------------------------
__global__ void k_finish(const float* __restrict__ spart, float* __restrict__ vsum,
                         const int* __restrict__ label, float* __restrict__ obj,
                         float* __restrict__ yprob, float* __restrict__ masked, int iter)
{
    const int b = blockIdx.x, t = threadIdx.x;
    if (t < 160) {
        const float* sp = spart + (size_t)b * 160 + t;
        float sv = 0.f;
        #pragma unroll 8
        for (int rc = 0; rc < 72; ++rc)
            sv += sp[(size_t)rc * 81920];
        float sq = sv * sv;
        sq += __shfl_xor(sq, 1); sq += __shfl_xor(sq, 2);
        sq += __shfl_xor(sq, 4); sq += __shfl_xor(sq, 8);
        float v = sv * (sq / (1.f + sq)) / sqrtf(sq + EPSF);
        float pv = (iter > 0) ? vsum[b * 160 + t] : 0.f;
        vsum[b * 160 + t] = pv + v;
        if (iter == 2) {
            obj[b * 160 + t] = v;
            float vv = v * v;
            vv += __shfl_xor(vv, 1); vv += __shfl_xor(vv, 2);
            vv += __shfl_xor(vv, 4); vv += __shfl_xor(vv, 8);
            int j = t >> 4;
            if ((t & 15) == 0) yprob[b * 10 + j] = sqrtf(vv + EPSF);
            masked[b * 160 + t] = (label[b] == j) ? v : 0.f;
        }
    }
}

// ---------------------------------------------------------------------------
// decoder GEMM: C[m,n] = act(bias[n] + sum_k A[m,k]*Wt[n,k]); M=512.
// ---------------------------------------------------------------------------
__global__ void k_mlp(const float* __restrict__ A, const float* __restrict__ Wt,
                      const float* __restrict__ bias, float* __restrict__ C,
                      int N, int K, int act)
{
    const int m0 = blockIdx.x * 32;
    const int n0 = blockIdx.y * 32;
    const int t  = threadIdx.x;
    const int tn = t & 31, tg = t >> 5;
    __shared__ float As[32][33];
    __shared__ float Ws[32][33];
    float acc[4] = {0.f, 0.f, 0.f, 0.f};
    for (int k0 = 0; k0 < K; k0 += 32) {
        __syncthreads();
        for (int idx = t; idx < 1024; idx += 256) {
            int rr = idx >> 5, kk = idx & 31;
            As[rr][kk] = A[(size_t)(m0 + rr) * K + k0 + kk];
            int n = n0 + rr;
            Ws[rr][kk] = (n < N) ? Wt[(size_t)n * K + k0 + kk] : 0.f;
        }
        __syncthreads();
        #pragma unroll 8
        for (int kk = 0; kk < 32; ++kk) {
            float bv = Ws[tn][kk];
            #pragma unroll
            for (int i = 0; i < 4; ++i)
                acc[i] += As[tg * 4 + i][kk] * bv;
        }
    }
    int n = n0 + tn;
    if (n < N) {
        float bs = bias[n];
        #pragma unroll
        for (int i = 0; i < 4; ++i) {
            float vv = acc[i] + bs;
            vv = (act == 0) ? fmaxf(vv, 0.f) : 1.f / (1.f + expf(-vv));
            C[(size_t)(m0 + tg * 4 + i) * N + n] = vv;
        }
    }
}

// ---------------------------------------------------------------------------
extern "C" void kernel_launch(void* const* d_in, const int* in_sizes, int n_in,
                              void* d_out, int out_size, void* d_ws, size_t ws_size,
                              hipStream_t stream)
{
    const float* image  = (const float*)d_in[0];
    const int*   label  = (const int*)  d_in[1];
    const float* conv_w = (const float*)d_in[2];
    const float* conv_b = (const float*)d_in[3];
    const float* pc_w   = (const float*)d_in[4];
    const float* pc_b   = (const float*)d_in[5];
    const float* Wrt    = (const float*)d_in[6];
    const float* dw1 = (const float*)d_in[7];
    const float* db1 = (const float*)d_in[8];
    const float* dw2 = (const float*)d_in[9];
    const float* db2 = (const float*)d_in[10];
    const float* dw3 = (const float*)d_in[11];
    const float* db3 = (const float*)d_in[12];
    float* out = (float*)d_out;

    char* p = (char*)d_ws;
    __hip_bfloat16* xt  = (__hip_bfloat16*)p; p += 104857600;
    float* u      = (float*)p; p += 18874368;
    __hip_bfloat16* Bw2 = (__hip_bfloat16*)p; p += 10616832;
    float* vsum   = (float*)p; p += 327680;
    float* masked = (float*)p; p += 327680;
    float* h1     = (float*)p; p += 1048576;
    float* h2     = (float*)p; p += 2097152;

    // spart [72][512][160] f32 (23.6 MB) aliases xt: xt is dead after k_conv2,
    // and conv1 fully rewrites it each launch -> deterministic across replays.
    float* spart = (float*)xt;

    float* obj   = out;            // [512,10,16,1]
    float* recon = out + 81920;    // [512,1,28,28]
    float* yprob = out + 483328;   // [512,10]

    k_bw2<<<256, 256, 0, stream>>>(pc_w, Bw2);
    k_conv1<<<512, 256, 0, stream>>>(image, conv_w, conv_b, xt);
    k_conv2<<<256, 512, 0, stream>>>(xt, Bw2, pc_b, u);
    k_squash_u<<<2304, 256, 0, stream>>>(u, 589824);
    for (int it = 0; it < 3; ++it) {
        k_route3<<<dim3(72, 16), 256, 0, stream>>>(u, Wrt, vsum, spart, it);
        k_finish<<<512, 192, 0, stream>>>(spart, vsum, label, obj, yprob, masked, it);
    }
    k_mlp<<<dim3(16, 16), 256, 0, stream>>>(masked, dw1, db1, h1, 512, 160, 0);
    k_mlp<<<dim3(16, 32), 256, 0, stream>>>(h1, dw2, db2, h2, 1024, 512, 0);
    k_mlp<<<dim3(16, 25), 256, 0, stream>>>(h2, dw3, db3, recon, 784, 1024, 1);
}

// Round 8
// 757.346 us; speedup vs baseline: 3.5845x; 2.7407x over previous
//
#include <hip/hip_runtime.h>
#include <hip/hip_bf16.h>

#define EPSF 1e-8f

typedef __attribute__((ext_vector_type(8))) short short8v;
typedef __attribute__((ext_vector_type(4))) float float4v;

static __device__ __forceinline__ unsigned short f2bf_bits(float x)
{
    return __builtin_bit_cast(unsigned short, __float2bfloat16(x));
}

// ---------------------------------------------------------------------------
// Bw2 transform: pc_w f32 [256oc][256ic][81k] -> coalesced per-wave chunks:
//   chunk_id = ((kidx*8+icc)*4+wc)*4+nt ; within chunk lane(slot*16+r16)*8+i
// ---------------------------------------------------------------------------
__global__ __launch_bounds__(256) void k_bw2(const float* __restrict__ pw,
                                             __hip_bfloat16* __restrict__ Bw2)
{
    const int oc = blockIdx.x;
    const int t = threadIdx.x;
    __shared__ unsigned short wl[20736];   // [ic][k] bf16 bits
    for (int i = t; i < 20736; i += 256)
        wl[i] = f2bf_bits(pw[(size_t)oc * 20736 + i]);
    __syncthreads();
    const int r16 = oc & 15, nt = (oc >> 4) & 3, wcq = oc >> 6;
    for (int e = t; e < 2592; e += 256) {
        const int kidx = e >> 5, icc = (e >> 2) & 7, slot = e & 3;
        short8v v;
        #pragma unroll
        for (int i = 0; i < 8; ++i)
            v[i] = (short)wl[(icc * 32 + slot * 8 + i) * 81 + kidx];
        const int chunk = ((kidx * 8 + icc) * 4 + wcq) * 4 + nt;
        *(short8v*)(Bw2 + (size_t)chunk * 512 + (slot * 16 + r16) * 8) = v;
    }
}

// ---------------------------------------------------------------------------
// conv1: image[512,1,28,28] * cw[256,1,9,9] + cb -> relu
//   -> x_t bf16 [b][icc=8][pos=400][64B unit, slot-XOR-permuted]
// ---------------------------------------------------------------------------
__global__ __launch_bounds__(256) void k_conv1(const float* __restrict__ img,
                                               const float* __restrict__ cw,
                                               const float* __restrict__ cb,
                                               __hip_bfloat16* __restrict__ xt)
{
    const int b = blockIdx.x;
    const int c = threadIdx.x;
    __shared__ float simg[784];
    for (int i = c; i < 784; i += 256) simg[i] = img[b * 784 + i];
    float wreg[81];
    const float* wp = cw + c * 81;
    #pragma unroll
    for (int k = 0; k < 81; ++k) wreg[k] = wp[k];
    const float bias = cb[c];
    __syncthreads();

    const int icc = c >> 5, slot = (c >> 3) & 3, ic8 = c & 7;
    char* xbase = (char*)xt + ((size_t)b * 8 + icc) * 25600;

    for (int h = 0; h < 20; ++h) {
        for (int wg = 0; wg < 5; ++wg) {
            float acc[4] = {bias, bias, bias, bias};
            #pragma unroll
            for (int ky = 0; ky < 9; ++ky) {
                const float* rp = &simg[(h + ky) * 28 + wg * 4];
                float v[12];
                #pragma unroll
                for (int i = 0; i < 12; ++i) v[i] = rp[i];
                #pragma unroll
                for (int kx = 0; kx < 9; ++kx) {
                    const float wv = wreg[ky * 9 + kx];
                    #pragma unroll
                    for (int i = 0; i < 4; ++i)
                        acc[i] = fmaf(v[kx + i], wv, acc[i]);
                }
            }
            #pragma unroll
            for (int i = 0; i < 4; ++i) {
                int w = wg * 4 + i;
                float av = fmaxf(acc[i], 0.f);
                int pos = h * 20 + (w & 1) * 10 + (w >> 1);
                int off = pos * 64 + ((slot ^ ((pos >> 1) & 3)) << 4) + ic8 * 2;
                *(unsigned short*)(xbase + off) = f2bf_bits(av);
            }
        }
    }
}

// ---------------------------------------------------------------------------
// async stage of one icc-chunk (2 images, 51200 B) into LDS via global_load_lds
// ---------------------------------------------------------------------------
__device__ __forceinline__ void stage_x(const __hip_bfloat16* __restrict__ xt,
                                        char* dst, int b0, int icc, int t)
{
    const __hip_bfloat16* base0 = xt + ((size_t)(b0    ) * 8 + icc) * 12800;
    const __hip_bfloat16* base1 = xt + ((size_t)(b0 + 1) * 8 + icc) * 12800;
    #pragma unroll
    for (int k = 0; k < 6; ++k) {
        const int unit = t + k * 512;
        const __hip_bfloat16* gp = (unit < 1600) ? (base0 + unit * 8)
                                                 : (base1 + (unit - 1600) * 8);
        __builtin_amdgcn_global_load_lds(
            (const __attribute__((address_space(1))) unsigned int*)gp,
            (__attribute__((address_space(3))) unsigned int*)(dst + unit * 16),
            16, 0, 0);
    }
    if (t < 128) {
        const int unit = 3072 + t;
        const __hip_bfloat16* gp = base1 + (unit - 1600) * 8;
        __builtin_amdgcn_global_load_lds(
            (const __attribute__((address_space(1))) unsigned int*)gp,
            (__attribute__((address_space(3))) unsigned int*)(dst + unit * 16),
            16, 0, 0);
    }
}

// ---------------------------------------------------------------------------
// conv2 via MFMA: grid 256 (2 b each), 512 thr = 8 waves (wr=img, wc=64-oc).
// Double-buffered LDS (2x51.2KB), async global_load_lds, 1 barrier per icc.
// ---------------------------------------------------------------------------
__global__ __launch_bounds__(512) void k_conv2(const __hip_bfloat16* __restrict__ xt,
                                               const __hip_bfloat16* __restrict__ Bw2,
                                               const float* __restrict__ pcb,
                                               float* __restrict__ u)
{
    const int b0 = blockIdx.x * 2;
    const int t = threadIdx.x;
    const int lane = t & 63, wid = t >> 6;
    const int wr = wid >> 2, wc = wid & 3;
    const int r16 = lane & 15, slot = lane >> 4;

    __shared__ alignas(16) char xs[2][51200];

    int lc[3];
    #pragma unroll
    for (int mt = 0; mt < 3; ++mt) {
        int hw = mt * 16 + r16;
        if (hw >= 36) hw = 0;
        int h = hw / 6, w = hw - h * 6;
        lc[mt] = 40 * h + w;
    }

    float4v acc[3][4];
    #pragma unroll
    for (int mt = 0; mt < 3; ++mt)
        #pragma unroll
        for (int nt = 0; nt < 4; ++nt)
            acc[mt][nt] = (float4v){0.f, 0.f, 0.f, 0.f};

    stage_x(xt, xs[0], b0, 0, t);
    __syncthreads();

    for (int icc = 0; icc < 8; ++icc) {
        const int cur = icc & 1;
        if (icc < 7) stage_x(xt, xs[cur ^ 1], b0, icc + 1, t);

        const char* xw = xs[cur] + wr * 25600;
        const size_t bK = ((size_t)icc * 4 + wc) * 2048 + lane * 8;

        #pragma unroll 3
        for (int kidx = 0; kidx < 81; ++kidx) {
            int ky = kidx / 9, kx = kidx - ky * 9;
            int scalK = 20 * ky + 10 * (kx & 1) + (kx >> 1);
            short8v a[3];
            #pragma unroll
            for (int mt = 0; mt < 3; ++mt) {
                int pos = lc[mt] + scalK;
                int off = pos * 64 + (((slot ^ (pos >> 1)) & 3) << 4);
                a[mt] = *(const short8v*)(xw + off);
            }
            const __hip_bfloat16* bp = Bw2 + (size_t)kidx * 65536 + bK;
            short8v bv[4];
            #pragma unroll
            for (int nt = 0; nt < 4; ++nt)
                bv[nt] = *(const short8v*)(bp + nt * 512);
            #pragma unroll
            for (int mt = 0; mt < 3; ++mt)
                #pragma unroll
                for (int nt = 0; nt < 4; ++nt)
                    acc[mt][nt] = __builtin_amdgcn_mfma_f32_16x16x32_bf16(a[mt], bv[nt], acc[mt][nt], 0, 0, 0);
        }
        __syncthreads();
    }

    const int b = b0 + wr;
    #pragma unroll
    for (int mt = 0; mt < 3; ++mt) {
        int hwb = mt * 16 + slot * 4;
        if (hwb < 36) {
            #pragma unroll
            for (int nt = 0; nt < 4; ++nt) {
                int oc = wc * 64 + nt * 16 + r16;
                float pb = pcb[oc];
                float4v v = acc[mt][nt];
                v.x += pb; v.y += pb; v.z += pb; v.w += pb;
                *(float4v*)(u + (size_t)b * 9216 + oc * 36 + hwb) = v;
            }
        }
    }
}

// ---------------------------------------------------------------------------
// squash groups of 8 (in place)
// ---------------------------------------------------------------------------
__global__ void k_squash_u(float* __restrict__ u, int ngroups)
{
    int g = blockIdx.x * blockDim.x + threadIdx.x;
    if (g >= ngroups) return;
    float4v* p = (float4v*)(u + (size_t)g * 8);
    float4v a = p[0], c = p[1];
    float sq = a.x * a.x + a.y * a.y + a.z * a.z + a.w * a.w
             + c.x * c.x + c.y * c.y + c.z * c.z + c.w * c.w;
    float scale = (sq / (1.f + sq)) / sqrtf(sq + EPSF);
    a *= scale; c *= scale;
    p[0] = a; p[1] = c;
}

// ---------------------------------------------------------------------------
// routing: grid 1152 = 144 rc (8 W-rows) x 8 bc (64 images); 256 thr.
// bid%8 == rc%8 -> all 8 bc-copies of an rc land on one XCD (L2-resident W).
// Thread = (oq quarter, image); r-loop serial -> NO cross-lane r-reduce.
// W 40KB LDS f32 (XOR-swizzled, oq-conflict-free); u tile 17KB LDS.
// ---------------------------------------------------------------------------
__global__ __launch_bounds__(256, 2) void k_route3(const float* __restrict__ u,
                                                   const float* __restrict__ W,
                                                   const float* __restrict__ vsum,
                                                   float* __restrict__ spart, int iter)
{
    const int bid = blockIdx.x;
    const int rc = bid % 144;
    const int bc = bid / 144;
    const int r0 = rc * 8;
    const int b0 = bc * 64;
    const int t = threadIdx.x;
    const int oq = t & 3;
    const int img = t >> 2;           // 0..63
    const int b = b0 + img;

    __shared__ alignas(16) float Wl[10240];    // 40KB: 8 rows x 320 f4 units, swizzled
    __shared__ alignas(16) float ul[64 * 68];  // 17.4KB: u tile, padded stride 68

    // stage W rows r0..r0+7 (coalesced read; store unit e -> e ^ ((e>>3)&3))
    #pragma unroll
    for (int k = 0; k < 10; ++k) {
        int e = t + k * 256;
        int rr = e / 320, rest = e - rr * 320;
        float4v val = *(const float4v*)(W + (size_t)(r0 + rr) * 1280 + rest * 4);
        int es = e ^ ((e >> 3) & 3);
        *(float4v*)(Wl + es * 4) = val;
    }
    // stage u tile: 64 images x 64 floats (8 r x 8 c)
    #pragma unroll
    for (int k = 0; k < 4; ++k) {
        int e = t + k * 256;
        int im = e >> 4, f4 = e & 15;
        float4v val = *(const float4v*)(u + (size_t)(b0 + im) * 9216 + rc * 64 + f4 * 4);
        *(float4v*)(ul + im * 68 + f4 * 4) = val;
    }
    __syncthreads();

    float4v vv[10];
    if (iter > 0) {
        #pragma unroll
        for (int j = 0; j < 10; ++j)
            vv[j] = *(const float4v*)(vsum + (size_t)b * 160 + j * 16 + oq * 4);
    }

    float4v acc[10];
    #pragma unroll
    for (int j = 0; j < 10; ++j) acc[j] = (float4v){0.f, 0.f, 0.f, 0.f};

    const float* up = ul + img * 68;

    for (int r = 0; r < 8; ++r) {
        float4v u0 = *(const float4v*)(up + r * 8);
        float4v u1 = *(const float4v*)(up + r * 8 + 4);
        float4v uh[10];
        #pragma unroll
        for (int j = 0; j < 10; ++j) {
            #pragma unroll
            for (int oo = 0; oo < 4; ++oo) {
                int un = r * 320 + j * 32 + oq * 8 + oo * 2;
                int i0 = un ^ oq;           // (un>>3)&3 == oq here
                int i1 = i0 ^ 1;            // un+1 swizzled
                float4v wlo = *(const float4v*)(Wl + i0 * 4);
                float4v whi = *(const float4v*)(Wl + i1 * 4);
                uh[j][oo] = wlo.x * u0.x + wlo.y * u0.y + wlo.z * u0.z + wlo.w * u0.w
                          + whi.x * u1.x + whi.y * u1.y + whi.z * u1.z + whi.w * u1.w;
            }
        }
        if (iter > 0) {
            float q[10];
            #pragma unroll
            for (int j = 0; j < 10; ++j) {
                float qp = uh[j].x * vv[j].x + uh[j].y * vv[j].y
                         + uh[j].z * vv[j].z + uh[j].w * vv[j].w;
                qp += __shfl_xor(qp, 1);
                qp += __shfl_xor(qp, 2);
                q[j] = qp;
            }
            float mx = q[0];
            #pragma unroll
            for (int j = 1; j < 10; ++j) mx = fmaxf(mx, q[j]);
            float ssum = 0.f;
            float c[10];
            #pragma unroll
            for (int j = 0; j < 10; ++j) { c[j] = __expf(q[j] - mx); ssum += c[j]; }
            float inv = 1.f / ssum;
            #pragma unroll
            for (int j = 0; j < 10; ++j) acc[j] += (c[j] * inv) * uh[j];
        } else {
            #pragma unroll
            for (int j = 0; j < 10; ++j) acc[j] += 0.1f * uh[j];
        }
    }

    float* dst = spart + ((size_t)rc * 512 + b) * 160 + oq * 4;
    #pragma unroll
    for (int j = 0; j < 10; ++j)
        *(float4v*)(dst + j * 16) = acc[j];
}

// ---------------------------------------------------------------------------
// finish: sum 144 partials -> squash -> v; vsum update; iter==2 writes outputs
// ---------------------------------------------------------------------------
__global__ void k_finish(const float* __restrict__ spart, float* __restrict__ vsum,
                         const int* __restrict__ label, float* __restrict__ obj,
                         float* __restrict__ yprob, float* __restrict__ masked, int iter)
{
    const int b = blockIdx.x, t = threadIdx.x;
    if (t < 160) {
        const float* sp = spart + (size_t)b * 160 + t;
        float sv = 0.f;
        #pragma unroll 8
        for (int rc = 0; rc < 144; ++rc)
            sv += sp[(size_t)rc * 81920];
        float sq = sv * sv;
        sq += __shfl_xor(sq, 1); sq += __shfl_xor(sq, 2);
        sq += __shfl_xor(sq, 4); sq += __shfl_xor(sq, 8);
        float v = sv * (sq / (1.f + sq)) / sqrtf(sq + EPSF);
        float pv = (iter > 0) ? vsum[b * 160 + t] : 0.f;
        vsum[b * 160 + t] = pv + v;
        if (iter == 2) {
            obj[b * 160 + t] = v;
            float vv = v * v;
            vv += __shfl_xor(vv, 1); vv += __shfl_xor(vv, 2);
            vv += __shfl_xor(vv, 4); vv += __shfl_xor(vv, 8);
            int j = t >> 4;
            if ((t & 15) == 0) yprob[b * 10 + j] = sqrtf(vv + EPSF);
            masked[b * 160 + t] = (label[b] == j) ? v : 0.f;
        }
    }
}

// ---------------------------------------------------------------------------
// decoder GEMM: C[m,n] = act(bias[n] + sum_k A[m,k]*Wt[n,k]); M=512.
// ---------------------------------------------------------------------------
__global__ void k_mlp(const float* __restrict__ A, const float* __restrict__ Wt,
                      const float* __restrict__ bias, float* __restrict__ C,
                      int N, int K, int act)
{
    const int m0 = blockIdx.x * 32;
    const int n0 = blockIdx.y * 32;
    const int t  = threadIdx.x;
    const int tn = t & 31, tg = t >> 5;
    __shared__ float As[32][33];
    __shared__ float Ws[32][33];
    float acc[4] = {0.f, 0.f, 0.f, 0.f};
    for (int k0 = 0; k0 < K; k0 += 32) {
        __syncthreads();
        for (int idx = t; idx < 1024; idx += 256) {
            int rr = idx >> 5, kk = idx & 31;
            As[rr][kk] = A[(size_t)(m0 + rr) * K + k0 + kk];
            int n = n0 + rr;
            Ws[rr][kk] = (n < N) ? Wt[(size_t)n * K + k0 + kk] : 0.f;
        }
        __syncthreads();
        #pragma unroll 8
        for (int kk = 0; kk < 32; ++kk) {
            float bv = Ws[tn][kk];
            #pragma unroll
            for (int i = 0; i < 4; ++i)
                acc[i] += As[tg * 4 + i][kk] * bv;
        }
    }
    int n = n0 + tn;
    if (n < N) {
        float bs = bias[n];
        #pragma unroll
        for (int i = 0; i < 4; ++i) {
            float vv = acc[i] + bs;
            vv = (act == 0) ? fmaxf(vv, 0.f) : 1.f / (1.f + expf(-vv));
            C[(size_t)(m0 + tg * 4 + i) * N + n] = vv;
        }
    }
}

// ---------------------------------------------------------------------------
extern "C" void kernel_launch(void* const* d_in, const int* in_sizes, int n_in,
                              void* d_out, int out_size, void* d_ws, size_t ws_size,
                              hipStream_t stream)
{
    const float* image  = (const float*)d_in[0];
    const int*   label  = (const int*)  d_in[1];
    const float* conv_w = (const float*)d_in[2];
    const float* conv_b = (const float*)d_in[3];
    const float* pc_w   = (const float*)d_in[4];
    const float* pc_b   = (const float*)d_in[5];
    const float* Wrt    = (const float*)d_in[6];
    const float* dw1 = (const float*)d_in[7];
    const float* db1 = (const float*)d_in[8];
    const float* dw2 = (const float*)d_in[9];
    const float* db2 = (const float*)d_in[10];
    const float* dw3 = (const float*)d_in[11];
    const float* db3 = (const float*)d_in[12];
    float* out = (float*)d_out;

    char* p = (char*)d_ws;
    __hip_bfloat16* xt  = (__hip_bfloat16*)p; p += 104857600;
    float* u      = (float*)p; p += 18874368;
    __hip_bfloat16* Bw2 = (__hip_bfloat16*)p; p += 10616832;
    float* vsum   = (float*)p; p += 327680;
    float* masked = (float*)p; p += 327680;
    float* h1     = (float*)p; p += 1048576;
    float* h2     = (float*)p; p += 2097152;

    // spart [144][512][160] f32 (47.2 MB) aliases xt (dead after k_conv2,
    // fully rewritten by conv1 each launch -> deterministic across replays).
    float* spart = (float*)xt;

    float* obj   = out;            // [512,10,16,1]
    float* recon = out + 81920;    // [512,1,28,28]
    float* yprob = out + 483328;   // [512,10]

    k_bw2<<<256, 256, 0, stream>>>(pc_w, Bw2);
    k_conv1<<<512, 256, 0, stream>>>(image, conv_w, conv_b, xt);
    k_conv2<<<256, 512, 0, stream>>>(xt, Bw2, pc_b, u);
    k_squash_u<<<2304, 256, 0, stream>>>(u, 589824);
    for (int it = 0; it < 3; ++it) {
        k_route3<<<1152, 256, 0, stream>>>(u, Wrt, vsum, spart, it);
        k_finish<<<512, 192, 0, stream>>>(spart, vsum, label, obj, yprob, masked, it);
    }
    k_mlp<<<dim3(16, 16), 256, 0, stream>>>(masked, dw1, db1, h1, 512, 160, 0);
    k_mlp<<<dim3(16, 32), 256, 0, stream>>>(h1, dw2, db2, h2, 1024, 512, 0);
    k_mlp<<<dim3(16, 25), 256, 0, stream>>>(h2, dw3, db3, recon, 784, 1024, 1);
}